// Round 1
// baseline (3757.859 us; speedup 1.0000x reference)
//
#include <hip/hip_runtime.h>
#include <hip/hip_bf16.h>
#include <math.h>

// Problem constants (B=32, T=256, V=32000, D=512)
#define R   8192    // B*T rows
#define TT  256     // T
#define D   512
#define V   32000
#define G3  1536    // 3*D (z|f|o)
#define K2  1024    // 2*D ([x_prev | x])

// ---------------- embedding gather ----------------
__global__ __launch_bounds__(256) void embed_kernel(const int* __restrict__ tok,
                                                    const float4* __restrict__ emb,
                                                    float4* __restrict__ X) {
  int idx = blockIdx.x * 256 + threadIdx.x;     // over R*128 float4s
  int row = idx >> 7;
  int c   = idx & 127;
  int t   = tok[row];
  X[idx] = emb[(size_t)t * 128 + c];
}

// ---------------- QRNN pre-activation GEMM ----------------
// PRE[r, g*512+e] = sum_d xprev[r,d]*Wg[0][d][e] + x[r,d]*Wg[1][d][e] + bg[e]
// Treated as (R x 1024) @ (1024 x 1536): A cols [0,512) = x shifted by one t
// (zeros at t==0), cols [512,1024) = x. B rows [0,512)->Wg[0], [512,1024)->Wg[1].
// Tiles: 128x128 C per block, BK=16, 256 threads, 8x8 micro-tile.
__global__ __launch_bounds__(256) void pre_gemm(const float* __restrict__ X,
    const float* __restrict__ Wz, const float* __restrict__ Wf, const float* __restrict__ Wo,
    const float* __restrict__ bz, const float* __restrict__ bf, const float* __restrict__ bo,
    float* __restrict__ PRE) {
  __shared__ float As[16][132];   // [k][m], row = 528B (16B aligned)
  __shared__ float Bs[16][132];   // [k][n]
  const int t   = threadIdx.x;
  const int ty  = t >> 4, tx = t & 15;
  const int row0 = blockIdx.x * 128;
  const int col0 = blockIdx.y * 128;          // 128 | 512, so gate constant per block
  const int gate = col0 >> 9;
  const float* Wg = (gate == 0) ? Wz : (gate == 1 ? Wf : Wo);
  const float* bg = (gate == 0) ? bz : (gate == 1 ? bf : bo);
  const int ecol0 = col0 & 511;
  const int lr  = t >> 2;          // A-load row within 64-row pass
  const int lc  = (t & 3) * 4;     // A-load k (float4)
  const int brr = t >> 5;          // B-load k-row within 8-row pass
  const int bcc = (t & 31) * 4;    // B-load col (float4)
  float acc[8][8] = {};

  for (int k0 = 0; k0 < K2; k0 += 16) {
#pragma unroll
    for (int p = 0; p < 2; ++p) {
      int r  = row0 + lr + p * 64;
      int k  = k0 + lc;
      float4 a4;
      if (k < D) {  // x_prev part
        if (r & (TT - 1)) a4 = *(const float4*)(X + (size_t)(r - 1) * D + k);
        else              a4 = make_float4(0.f, 0.f, 0.f, 0.f);
      } else {      // x part
        a4 = *(const float4*)(X + (size_t)r * D + (k - D));
      }
      int rr = lr + p * 64;
      As[lc + 0][rr] = a4.x; As[lc + 1][rr] = a4.y;
      As[lc + 2][rr] = a4.z; As[lc + 3][rr] = a4.w;
    }
#pragma unroll
    for (int p = 0; p < 2; ++p) {
      int kk = k0 + brr + p * 8;
      int i  = kk >> 9;
      int dd = kk & 511;
      float4 b4 = *(const float4*)(Wg + (size_t)i * (D * D) + (size_t)dd * D + ecol0 + bcc);
      *(float4*)(&Bs[brr + p * 8][bcc]) = b4;
    }
    __syncthreads();
#pragma unroll
    for (int k = 0; k < 16; ++k) {
      float a[8], b[8];
      *(float4*)(a)     = *(const float4*)(&As[k][ty * 8]);
      *(float4*)(a + 4) = *(const float4*)(&As[k][ty * 8 + 4]);
      *(float4*)(b)     = *(const float4*)(&Bs[k][tx * 8]);
      *(float4*)(b + 4) = *(const float4*)(&Bs[k][tx * 8 + 4]);
#pragma unroll
      for (int i = 0; i < 8; ++i)
#pragma unroll
        for (int j = 0; j < 8; ++j)
          acc[i][j] += a[i] * b[j];
    }
    __syncthreads();
  }
  // epilogue: + bias, store
  float bv[8];
#pragma unroll
  for (int j = 0; j < 8; ++j) bv[j] = bg[ecol0 + tx * 8 + j];
#pragma unroll
  for (int i = 0; i < 8; ++i) {
    int r = row0 + ty * 8 + i;
    float* dst = PRE + (size_t)r * G3 + col0 + tx * 8;
    float4 v0 = make_float4(acc[i][0] + bv[0], acc[i][1] + bv[1],
                            acc[i][2] + bv[2], acc[i][3] + bv[3]);
    float4 v1 = make_float4(acc[i][4] + bv[4], acc[i][5] + bv[5],
                            acc[i][6] + bv[6], acc[i][7] + bv[7]);
    *(float4*)dst       = v0;
    *(float4*)(dst + 4) = v1;
  }
}

// ---------------- fo-pool scan + output gate ----------------
// one thread per (b,d); c_t = f*c + (1-f)*z; h = o*c
__global__ __launch_bounds__(256) void scan_kernel(const float* __restrict__ PRE,
                                                   float* __restrict__ Y) {
  int idx = blockIdx.x * 256 + threadIdx.x;   // 0 .. 32*512-1
  int b = idx >> 9;
  int d = idx & 511;
  const float* p = PRE + (size_t)b * TT * G3 + d;
  float*       y = Y   + (size_t)b * TT * D  + d;
  float c = 0.f;
  for (int t = 0; t < TT; ++t) {
    float pz = p[0], pf = p[512], po = p[1024];
    float z = tanhf(pz);
    float f = 1.f / (1.f + __expf(-pf));
    float o = 1.f / (1.f + __expf(-po));
    c = f * c + (1.f - f) * z;
    *y = o * c;
    p += G3; y += D;
  }
}

// ---------------- zero helper ----------------
__global__ void zero_kernel(float* __restrict__ p, int n) {
  int i = blockIdx.x * 256 + threadIdx.x;
  if (i < n) p[i] = 0.f;
}

// ---------------- streamed logits: sumexp + target logit ----------------
// C tile 128x128, K=512. Logits are small (|h|<1, w~N(0,0.05^2)) -> exp safe
// without max-subtraction in fp32.
__global__ __launch_bounds__(256) void lse_gemm(const float* __restrict__ H,
    const float* __restrict__ W, const float* __restrict__ bias,
    const int* __restrict__ tgt, float* __restrict__ sumexp, float* __restrict__ tgl) {
  __shared__ float As[16][132];
  __shared__ float Bs[16][132];
  const int t   = threadIdx.x;
  const int ty  = t >> 4, tx = t & 15;
  const int row0 = blockIdx.x * 128;
  const int col0 = blockIdx.y * 128;
  const int lr  = t >> 2;
  const int lc  = (t & 3) * 4;
  const int brr = t >> 5;
  const int bcc = (t & 31) * 4;
  float acc[8][8] = {};

  for (int k0 = 0; k0 < D; k0 += 16) {
#pragma unroll
    for (int p = 0; p < 2; ++p) {
      int r  = row0 + lr + p * 64;
      float4 a4 = *(const float4*)(H + (size_t)r * D + k0 + lc);
      int rr = lr + p * 64;
      As[lc + 0][rr] = a4.x; As[lc + 1][rr] = a4.y;
      As[lc + 2][rr] = a4.z; As[lc + 3][rr] = a4.w;
    }
#pragma unroll
    for (int p = 0; p < 2; ++p) {
      int kk = k0 + brr + p * 8;
      float4 b4 = *(const float4*)(W + (size_t)kk * V + col0 + bcc);
      *(float4*)(&Bs[brr + p * 8][bcc]) = b4;
    }
    __syncthreads();
#pragma unroll
    for (int k = 0; k < 16; ++k) {
      float a[8], b[8];
      *(float4*)(a)     = *(const float4*)(&As[k][ty * 8]);
      *(float4*)(a + 4) = *(const float4*)(&As[k][ty * 8 + 4]);
      *(float4*)(b)     = *(const float4*)(&Bs[k][tx * 8]);
      *(float4*)(b + 4) = *(const float4*)(&Bs[k][tx * 8 + 4]);
#pragma unroll
      for (int i = 0; i < 8; ++i)
#pragma unroll
        for (int j = 0; j < 8; ++j)
          acc[i][j] += a[i] * b[j];
    }
    __syncthreads();
  }
  // epilogue: bias, exp, per-row partial sums; capture target logit
  const int colbase = col0 + tx * 8;
  float bv[8];
#pragma unroll
  for (int j = 0; j < 8; ++j) bv[j] = bias[colbase + j];
#pragma unroll
  for (int i = 0; i < 8; ++i) {
    int r  = row0 + ty * 8 + i;
    int tg = tgt[r];
    float s = 0.f;
#pragma unroll
    for (int j = 0; j < 8; ++j) {
      float v = acc[i][j] + bv[j];
      if (colbase + j == tg) tgl[r] = v;   // exactly one writer per row
      s += __expf(v);
    }
    // reduce across the 16 tx lanes (same ty -> contiguous 16-lane group)
#pragma unroll
    for (int m = 1; m < 16; m <<= 1) s += __shfl_xor(s, m, 64);
    if (tx == 0) atomicAdd(&sumexp[r], s);
  }
}

// ---------------- final cost ----------------
__global__ __launch_bounds__(256) void cost_kernel(const float* __restrict__ sumexp,
                                                   const float* __restrict__ tgl,
                                                   float* __restrict__ out) {
  int t = threadIdx.x;
  float s = 0.f;
  for (int r = t; r < R; r += 256) s += logf(sumexp[r]) - tgl[r];
#pragma unroll
  for (int m = 1; m < 64; m <<= 1) s += __shfl_xor(s, m, 64);
  __shared__ float red[4];
  int wave = t >> 6, lane = t & 63;
  if (lane == 0) red[wave] = s;
  __syncthreads();
  if (t == 0) out[0] = (red[0] + red[1] + red[2] + red[3]) / (float)R;
}

extern "C" void kernel_launch(void* const* d_in, const int* in_sizes, int n_in,
                              void* d_out, int out_size, void* d_ws, size_t ws_size,
                              hipStream_t stream) {
  const int*   tok = (const int*)d_in[0];
  const int*   tgt = (const int*)d_in[1];
  const float* emb = (const float*)d_in[2];
  const float* Wz0 = (const float*)d_in[3];  const float* bz0 = (const float*)d_in[4];
  const float* Wf0 = (const float*)d_in[5];  const float* bf0 = (const float*)d_in[6];
  const float* Wo0 = (const float*)d_in[7];  const float* bo0 = (const float*)d_in[8];
  const float* Wz1 = (const float*)d_in[9];  const float* bz1 = (const float*)d_in[10];
  const float* Wf1 = (const float*)d_in[11]; const float* bf1 = (const float*)d_in[12];
  const float* Wo1 = (const float*)d_in[13]; const float* bo1 = (const float*)d_in[14];
  const float* SW  = (const float*)d_in[15]; const float* SB  = (const float*)d_in[16];
  float* out = (float*)d_out;

  // workspace layout (floats): X[R*D] | Y[R*D] | PRE[R*3D] | SUM[R] | TGL[R]
  float* X   = (float*)d_ws;
  float* Y   = X + (size_t)R * D;
  float* PRE = Y + (size_t)R * D;
  float* SUM = PRE + (size_t)R * G3;
  float* TGL = SUM + R;

  // 1) embedding gather
  embed_kernel<<<R * 128 / 256, 256, 0, stream>>>(tok, (const float4*)emb, (float4*)X);
  // 2) layer 0
  pre_gemm<<<dim3(R / 128, G3 / 128), 256, 0, stream>>>(X, Wz0, Wf0, Wo0, bz0, bf0, bo0, PRE);
  scan_kernel<<<(32 * D) / 256, 256, 0, stream>>>(PRE, Y);
  // 3) layer 1
  pre_gemm<<<dim3(R / 128, G3 / 128), 256, 0, stream>>>(Y, Wz1, Wf1, Wo1, bz1, bf1, bo1, PRE);
  scan_kernel<<<(32 * D) / 256, 256, 0, stream>>>(PRE, X);
  // 4) streamed log-sum-exp over V + target logit
  zero_kernel<<<(R + 255) / 256, 256, 0, stream>>>(SUM, R);
  lse_gemm<<<dim3(R / 128, V / 128), 256, 0, stream>>>(X, SW, SB, tgt, SUM, TGL);
  // 5) mean NLL
  cost_kernel<<<1, 256, 0, stream>>>(SUM, TGL, out);
}

// Round 2
// 669.528 us; speedup vs baseline: 5.6127x; 5.6127x over previous
//
#include <hip/hip_runtime.h>
#include <hip/hip_bf16.h>
#include <math.h>

// Problem constants (B=32, T=256, V=32000, D=512)
#define R   8192    // B*T rows
#define TT  256
#define D   512
#define V   32000
#define G3  1536    // 3*D (z|f|o)

typedef __attribute__((ext_vector_type(8))) short bf16x8;
typedef __attribute__((ext_vector_type(4))) float f32x4;

__device__ __forceinline__ float bf2f(ushort u) {
  union { unsigned int i; float f; } x; x.i = ((unsigned int)u) << 16; return x.f;
}
__device__ __forceinline__ ushort f2bf(float f) {   // RNE
  union { float f; unsigned int i; } x; x.f = f;
  unsigned int r = x.i + 0x7fffu + ((x.i >> 16) & 1u);
  return (ushort)(r >> 16);
}

__device__ __forceinline__ void gload16(const void* g, void* l) {
  __builtin_amdgcn_global_load_lds((const __attribute__((address_space(1))) void*)g,
                                   (__attribute__((address_space(3))) void*)l, 16, 0, 0);
}

// ---------------- embedding gather -> XA bf16 [R][1024] = [x_prev | x] ----------------
__global__ __launch_bounds__(256) void embed_kernel(const int* __restrict__ tok,
                                                    const float4* __restrict__ emb,
                                                    ushort4* __restrict__ XA) {
  int idx = blockIdx.x * 256 + threadIdx.x;   // over R*128 float4s
  int r = idx >> 7, d4 = idx & 127;
  float4 v = emb[(size_t)tok[r] * 128 + d4];
  ushort4 h; h.x = f2bf(v.x); h.y = f2bf(v.y); h.z = f2bf(v.z); h.w = f2bf(v.w);
  XA[(size_t)r * 256 + 128 + d4] = h;                       // x part
  int t = r & (TT - 1);
  if (t < TT - 1) XA[(size_t)(r + 1) * 256 + d4] = h;       // next row's x_prev
  if (t == 0) { ushort4 z4; z4.x=z4.y=z4.z=z4.w=0; XA[(size_t)r * 256 + d4] = z4; }
}

// ---------------- weight transpose+convert: WcatT[1536][1024] bf16 ----------------
// WcatT[g*512+e][i*512+d] = Wg[i][d][e]
__global__ __launch_bounds__(256) void wconv(const float* __restrict__ Wz,
                                             const float* __restrict__ Wf,
                                             const float* __restrict__ Wo,
                                             ushort* __restrict__ WT) {
  __shared__ float tile[64][65];
  int z = blockIdx.z, g = z >> 1, i = z & 1;
  const float* src = (g == 0) ? Wz : (g == 1 ? Wf : Wo);
  src += (size_t)i * D * D;
  int d0 = blockIdx.x * 64, e0 = blockIdx.y * 64;
  int t = threadIdx.x, c = t & 63, rq = t >> 6;
#pragma unroll
  for (int p = 0; p < 16; ++p) {
    int dd = p * 4 + rq;
    tile[dd][c] = src[(size_t)(d0 + dd) * D + e0 + c];
  }
  __syncthreads();
#pragma unroll
  for (int p = 0; p < 16; ++p) {
    int ee = p * 4 + rq;
    WT[(size_t)(g * D + e0 + ee) * 1024 + i * D + d0 + c] = f2bf(tile[c][ee]);
  }
}

// ---------------- softmax weight transpose+convert: SWT[32000][512] bf16 ----------------
__global__ __launch_bounds__(256) void swconv(const float* __restrict__ SW,
                                              ushort* __restrict__ SWT) {
  __shared__ float tile[64][65];
  int k0 = blockIdx.x * 64, n0 = blockIdx.y * 64;
  int t = threadIdx.x, c = t & 63, rq = t >> 6;
#pragma unroll
  for (int p = 0; p < 16; ++p) {
    int kk = p * 4 + rq;
    tile[kk][c] = SW[(size_t)(k0 + kk) * V + n0 + c];
  }
  __syncthreads();
#pragma unroll
  for (int p = 0; p < 16; ++p) {
    int nn = p * 4 + rq;
    SWT[(size_t)(n0 + nn) * D + k0 + c] = f2bf(tile[c][nn]);
  }
}

// ---------------- bias concat ----------------
__global__ void bcat_kernel(const float* bz0, const float* bf0, const float* bo0,
                            const float* bz1, const float* bf1, const float* bo1,
                            float* BC0, float* BC1) {
  int idx = blockIdx.x * 256 + threadIdx.x;
  if (idx >= 2 * G3) return;
  int layer = idx / G3, rem = idx % G3, g = rem >> 9, e = rem & 511;
  const float* s = (layer == 0) ? (g == 0 ? bz0 : (g == 1 ? bf0 : bo0))
                                : (g == 0 ? bz1 : (g == 1 ? bf1 : bo1));
  (layer == 0 ? BC0 : BC1)[rem] = s[e];
}

// ---------------- bf16 MFMA GEMM core ----------------
// C[128x128] per 256-thread block (4 waves, 2x2 of 64x64 wave tiles, 4x4 frags).
// A row-major [M][K], B row-major-transposed [N][K] (both K-contiguous, bf16).
// LDS [128][64] bf16 linear; global source pre-swizzled so reads use slot^=(row&7)
// (rule #21: linear dest + inverse-swz source + swz on read).
template<int KTOT, int LDA, int LDB>
__device__ __forceinline__ void gemm_tile(const ushort* __restrict__ A,
                                          const ushort* __restrict__ B,
                                          int row0, int col0,
                                          char* As, char* Bs, f32x4 acc[4][4]) {
  const int t = threadIdx.x, lane = t & 63, w = t >> 6;
  const int wm = w >> 1, wn = w & 1;
  const int lrow = lane >> 3;            // row within 8-row chunk
  const int slot = (lane & 7) ^ lrow;    // inverse-swizzled source 16B slot
  const int lo = lane & 15, hi = lane >> 4;

  const ushort* ga0 = A + (size_t)(row0 + w * 32 + lrow) * LDA + slot * 8;
  const ushort* gb0 = B + (size_t)(col0 + w * 32 + lrow) * LDB + slot * 8;

#pragma unroll 1
  for (int k0 = 0; k0 < KTOT; k0 += 64) {
#pragma unroll
    for (int i = 0; i < 4; ++i) {
      int chunk = w * 4 + i;
      gload16(ga0 + (size_t)i * 8 * LDA + k0, As + chunk * 1024);
      gload16(gb0 + (size_t)i * 8 * LDB + k0, Bs + chunk * 1024);
    }
    __syncthreads();
#pragma unroll
    for (int ks = 0; ks < 2; ++ks) {
      bf16x8 av[4], bv[4];
#pragma unroll
      for (int mi = 0; mi < 4; ++mi) {
        int row = wm * 64 + mi * 16 + lo;
        int sl  = (ks * 4 + hi) ^ (row & 7);
        av[mi] = *(const bf16x8*)(As + row * 128 + sl * 16);
      }
#pragma unroll
      for (int ni = 0; ni < 4; ++ni) {
        int row = wn * 64 + ni * 16 + lo;
        int sl  = (ks * 4 + hi) ^ (row & 7);
        bv[ni] = *(const bf16x8*)(Bs + row * 128 + sl * 16);
      }
#pragma unroll
      for (int mi = 0; mi < 4; ++mi)
#pragma unroll
        for (int ni = 0; ni < 4; ++ni)
          acc[mi][ni] = __builtin_amdgcn_mfma_f32_16x16x32_bf16(av[mi], bv[ni], acc[mi][ni], 0, 0, 0);
    }
    __syncthreads();
  }
}

// ---------------- QRNN pre-activation GEMM (8192x1536x1024) ----------------
__global__ __launch_bounds__(256) void gemm_pre(const ushort* __restrict__ A,
                                                const ushort* __restrict__ B,
                                                const float* __restrict__ bcat,
                                                ushort* __restrict__ PRE) {
  __shared__ char lds[32768];
  f32x4 acc[4][4];
#pragma unroll
  for (int i = 0; i < 4; ++i)
#pragma unroll
    for (int j = 0; j < 4; ++j) { f32x4 z = {0.f,0.f,0.f,0.f}; acc[i][j] = z; }
  const int row0 = blockIdx.x * 128, col0 = blockIdx.y * 128;
  gemm_tile<1024,1024,1024>(A, B, row0, col0, lds, lds + 16384, acc);
  const int lane = threadIdx.x & 63, w = threadIdx.x >> 6;
  const int wm = w >> 1, wn = w & 1, lo = lane & 15, hi = lane >> 4;
#pragma unroll
  for (int ni = 0; ni < 4; ++ni) {
    int col = col0 + wn * 64 + ni * 16 + lo;
    float bb = bcat[col];
#pragma unroll
    for (int mi = 0; mi < 4; ++mi) {
      int r0 = row0 + wm * 64 + mi * 16 + hi * 4;
#pragma unroll
      for (int j = 0; j < 4; ++j)
        PRE[(size_t)(r0 + j) * G3 + col] = f2bf(acc[mi][ni][j] + bb);
    }
  }
}

// ---------------- logits GEMM (8192x32000x512) + fused exp-sum + target capture ----------------
__global__ __launch_bounds__(256) void gemm_lse(const ushort* __restrict__ A,
                                                const ushort* __restrict__ B,
                                                const float* __restrict__ SB,
                                                const int* __restrict__ tgt,
                                                float* __restrict__ SUM,
                                                float* __restrict__ TGL) {
  __shared__ char lds[32768];
  f32x4 acc[4][4];
#pragma unroll
  for (int i = 0; i < 4; ++i)
#pragma unroll
    for (int j = 0; j < 4; ++j) { f32x4 z = {0.f,0.f,0.f,0.f}; acc[i][j] = z; }
  const int row0 = blockIdx.x * 128, col0 = blockIdx.y * 128;
  gemm_tile<512,512,512>(A, B, row0, col0, lds, lds + 16384, acc);
  const int lane = threadIdx.x & 63, w = threadIdx.x >> 6;
  const int wm = w >> 1, wn = w & 1, lo = lane & 15, hi = lane >> 4;
#pragma unroll
  for (int mi = 0; mi < 4; ++mi) {
    int r0 = row0 + wm * 64 + mi * 16 + hi * 4;
    int tg[4];
    float s[4] = {0.f, 0.f, 0.f, 0.f};
#pragma unroll
    for (int j = 0; j < 4; ++j) tg[j] = tgt[r0 + j];
#pragma unroll
    for (int ni = 0; ni < 4; ++ni) {
      int col = col0 + wn * 64 + ni * 16 + lo;
      float bb = SB[col];
#pragma unroll
      for (int j = 0; j < 4; ++j) {
        float v = acc[mi][ni][j] + bb;
        if (col == tg[j]) TGL[r0 + j] = v;   // exactly one writer per row
        s[j] += __expf(v);
      }
    }
#pragma unroll
    for (int m = 1; m < 16; m <<= 1) {
#pragma unroll
      for (int j = 0; j < 4; ++j) s[j] += __shfl_xor(s[j], m, 64);
    }
    if (lo == 0) {
#pragma unroll
      for (int j = 0; j < 4; ++j) atomicAdd(&SUM[r0 + j], s[j]);
    }
  }
}

// ---------------- fo-pool scan (bf16 in, bf16 out in next-GEMM A layout) ----------------
// mode 0: OUT = YA [R][1024]: [r][512+d]=h(r), [r+1][d]=h(r) (t<255), [r][d]=0 (t==0)
// mode 1: OUT = H2 [R][512]
__global__ __launch_bounds__(256) void scan_kernel(const ushort* __restrict__ PRE,
                                                   ushort* __restrict__ OUT, int mode) {
  int idx = blockIdx.x * 256 + threadIdx.x;   // 32*512
  int b = idx >> 9, d = idx & 511;
  const ushort* p = PRE + (size_t)b * TT * G3 + d;
  float c = 0.f;
  for (int t0 = 0; t0 < TT; t0 += 8) {
    float pz[8], pf[8], po[8];
#pragma unroll
    for (int i = 0; i < 8; ++i) {
      const ushort* q = p + (size_t)(t0 + i) * G3;
      pz[i] = bf2f(q[0]); pf[i] = bf2f(q[512]); po[i] = bf2f(q[1024]);
    }
#pragma unroll
    for (int i = 0; i < 8; ++i) {
      float z = 2.f / (1.f + __expf(-2.f * pz[i])) - 1.f;
      float f = 1.f / (1.f + __expf(-pf[i]));
      float o = 1.f / (1.f + __expf(-po[i]));
      c = f * c + (1.f - f) * z;
      float h = o * c;
      int tt = t0 + i;
      size_t r = (size_t)b * TT + tt;
      ushort hb = f2bf(h);
      if (mode == 0) {
        OUT[r * 1024 + 512 + d] = hb;
        if (tt < TT - 1) OUT[(r + 1) * 1024 + d] = hb;
        if (tt == 0)     OUT[r * 1024 + d] = 0;
      } else {
        OUT[r * 512 + d] = hb;
      }
    }
  }
}

// ---------------- helpers ----------------
__global__ void zero_kernel(float* __restrict__ p, int n) {
  int i = blockIdx.x * 256 + threadIdx.x;
  if (i < n) p[i] = 0.f;
}

__global__ __launch_bounds__(256) void cost_kernel(const float* __restrict__ sumexp,
                                                   const float* __restrict__ tgl,
                                                   float* __restrict__ out) {
  int t = threadIdx.x;
  float s = 0.f;
  for (int r = t; r < R; r += 256) s += logf(sumexp[r]) - tgl[r];
#pragma unroll
  for (int m = 1; m < 64; m <<= 1) s += __shfl_xor(s, m, 64);
  __shared__ float red[4];
  int wave = t >> 6, lane = t & 63;
  if (lane == 0) red[wave] = s;
  __syncthreads();
  if (t == 0) out[0] = (red[0] + red[1] + red[2] + red[3]) / (float)R;
}

extern "C" void kernel_launch(void* const* d_in, const int* in_sizes, int n_in,
                              void* d_out, int out_size, void* d_ws, size_t ws_size,
                              hipStream_t stream) {
  const int*   tok = (const int*)d_in[0];
  const int*   tgt = (const int*)d_in[1];
  const float* emb = (const float*)d_in[2];
  const float* Wz0 = (const float*)d_in[3];  const float* bz0 = (const float*)d_in[4];
  const float* Wf0 = (const float*)d_in[5];  const float* bf0 = (const float*)d_in[6];
  const float* Wo0 = (const float*)d_in[7];  const float* bo0 = (const float*)d_in[8];
  const float* Wz1 = (const float*)d_in[9];  const float* bz1 = (const float*)d_in[10];
  const float* Wf1 = (const float*)d_in[11]; const float* bf1 = (const float*)d_in[12];
  const float* Wo1 = (const float*)d_in[13]; const float* bo1 = (const float*)d_in[14];
  const float* SW  = (const float*)d_in[15]; const float* SB  = (const float*)d_in[16];
  float* out = (float*)d_out;

  // workspace layout (bytes), total ~70.1 MB:
  char* base = (char*)d_ws;
  ushort* XA  = (ushort*)(base);               // 16,777,216  [R][1024] bf16
  ushort* YA  = (ushort*)(base + 16777216);    // 16,777,216  [R][1024] bf16
  ushort* PRE = (ushort*)(base + 33554432);    // 25,165,824  [R][1536] bf16
  ushort* H2  = (ushort*)(base + 58720256);    //  8,388,608  [R][512]  bf16
  ushort* WT0 = (ushort*)(base + 67108864);    //  3,145,728  [1536][1024] bf16
  ushort* WT1 = (ushort*)(base + 70254592);    //  3,145,728
  float*  BC0 = (float*)(base + 73400320);     //  6,144
  float*  BC1 = (float*)(base + 73406464);     //  6,144
  float*  SUM = (float*)(base + 73412608);     //  32,768
  float*  TGL = (float*)(base + 73445376);     //  32,768
  ushort* SWT = (ushort*)(base);               // alias over XA+YA (32,768,000 <= 33,554,432)

  embed_kernel<<<R * 128 / 256, 256, 0, stream>>>(tok, (const float4*)emb, (ushort4*)XA);
  wconv<<<dim3(8, 8, 6), 256, 0, stream>>>(Wz0, Wf0, Wo0, WT0);
  wconv<<<dim3(8, 8, 6), 256, 0, stream>>>(Wz1, Wf1, Wo1, WT1);
  bcat_kernel<<<12, 256, 0, stream>>>(bz0, bf0, bo0, bz1, bf1, bo1, BC0, BC1);

  gemm_pre<<<dim3(64, 12), 256, 0, stream>>>(XA, WT0, BC0, PRE);
  scan_kernel<<<64, 256, 0, stream>>>(PRE, YA, 0);
  gemm_pre<<<dim3(64, 12), 256, 0, stream>>>(YA, WT1, BC1, PRE);
  scan_kernel<<<64, 256, 0, stream>>>(PRE, H2, 1);

  // SWT aliases XA/YA — both dead after the second gemm_pre
  swconv<<<dim3(8, 500), 256, 0, stream>>>(SW, SWT);
  zero_kernel<<<32, 256, 0, stream>>>(SUM, R);
  gemm_lse<<<dim3(64, 250), 256, 0, stream>>>(H2, SWT, SB, tgt, SUM, TGL);
  cost_kernel<<<1, 256, 0, stream>>>(SUM, TGL, out);
}